// Round 14
// baseline (337.454 us; speedup 1.0000x reference)
//
#include <hip/hip_runtime.h>
#include <math.h>

#define L 8
#define N 32768
#define H 404
#define D 128
#define F 532
#define KT 9              // K-tiles of 64 (64*9=576; cols >=532 are zero in B)
#define GRU_BLOCKS 101    // one wave per hidden index

typedef __attribute__((ext_vector_type(8))) _Float16 half8;
typedef __attribute__((ext_vector_type(4))) float f32x4;
typedef __attribute__((address_space(3))) unsigned int as3_u32;
typedef __attribute__((address_space(1))) unsigned int as1_u32;

// workspace layout (float offsets)
#define WS_WH2     0                        // 9*128*64 fp16 = 36864 floats (pre-swizzled B tiles)
#define WS_HMAXK   (WS_WH2 + 36864)         // 8*128 uint keys
#define WS_HSEL    (WS_HMAXK + L * D)       // 7*128
#define WS_GI      (WS_HSEL + (L - 1) * D)  // 8*1212
#define WS_HBUF    (WS_GI + L * 3 * H)      // 2*404
#define WS_V       (WS_HBUF + 2 * H)        // 532
#define WS_HS      (WS_V + F)               // 128
#define WS_SCAL    (WS_HS + D)              // c, M, S, spare
#define WS_CNT     (WS_SCAL + 4)            // gru barrier counter
#define WS_LOGITS  (WS_CNT + 4)             // 32769
#define WS_HMAXK2  90000                    // dup-run scratch (timing instrument)
#define WS_HSEL2   (WS_HMAXK2 + L * D)

__device__ __forceinline__ unsigned encf(float f) {
    unsigned u = __float_as_uint(f);
    return (u & 0x80000000u) ? ~u : (u | 0x80000000u);
}
__device__ __forceinline__ float decf(unsigned u) {
    unsigned b = (u & 0x80000000u) ? (u ^ 0x80000000u) : ~u;
    return __uint_as_float(b);
}
__device__ __forceinline__ float sigmoidf_(float x) {
    return 1.0f / (1.0f + __expf(-x));
}
__device__ __forceinline__ unsigned pk_f16(float a, float b) {
    auto h = __builtin_amdgcn_cvt_pkrtz(a, b);
    return *(unsigned*)&h;
}
__device__ __forceinline__ half8 pack8(float4 x0, float4 x1) {
    uint4 u = { pk_f16(x0.x, x0.y), pk_f16(x0.z, x0.w),
                pk_f16(x1.x, x1.y), pk_f16(x1.z, x1.w) };
    return *(half8*)&u;
}
__device__ __forceinline__ void gld16(const void* g, void* l) {
    __builtin_amdgcn_global_load_lds((const as1_u32*)g, (as3_u32*)l, 16, 0, 0);
}

// ---- prep: pre-swizzled fp16 B tiles; init keys ----
__global__ void k_prep(const float* __restrict__ Wfa, unsigned short* __restrict__ wh2,
                       unsigned* __restrict__ keys, unsigned* __restrict__ cnt) {
    int i = blockIdx.x * 256 + threadIdx.x;
    if (i < L * D) keys[i] = 0u;           // decodes below all finite values
    if (i == 2000) *cnt = 0u;
    if (i >= KT * 128 * 8) return;
    int kt = i / (128 * 8);
    int rem = i - kt * 128 * 8;
    int c = rem >> 3, j = rem & 7;
    int k0 = kt * 64 + (j ^ (c & 7)) * 8;
    unsigned short v[8];
#pragma unroll
    for (int e = 0; e < 8; ++e) {
        int k = k0 + e;
        float x = (k < F) ? Wfa[c * F + k] : 0.0f;
        _Float16 h = (_Float16)x;
        v[e] = *(unsigned short*)&h;
    }
    *(uint4*)(wh2 + (long)i * 8) = *(uint4*)v;
}

// ---- big einsum: async global_load_lds staging, consume-side fp32->fp16 cvt ----
__global__ __launch_bounds__(256, 3)
void k_big(const float* __restrict__ nb, const unsigned short* __restrict__ wh2,
           const float* __restrict__ bfa, const int* __restrict__ aid,
           unsigned* __restrict__ hmaxk, float* __restrict__ hsel) {
    __shared__ float As[128 * 64];          // 32 KB, row = 256 B = 16 chunks
    __shared__ unsigned short Bs[128 * 64]; // 16 KB, row = 128 B = 8 chunks

    const int bid = blockIdx.x;
    const int l_hop = bid >> 8;
    const int row0 = (bid & 255) * 128;
    const int tid = threadIdx.x;
    const int lane = tid & 63, w = tid >> 6;
    const int wm = w >> 1, wn = w & 1;
    const int lr = lane & 15, kg = lane >> 4;

    const float* xbase = nb + ((long)l_hop * N + row0) * F;

    f32x4 acc[4][4];
    float bv[4];
#pragma unroll
    for (int n = 0; n < 4; ++n) bv[n] = bfa[wn * 64 + n * 16 + lr];
#pragma unroll
    for (int m = 0; m < 4; ++m)
#pragma unroll
        for (int n = 0; n < 4; ++n) {
            acc[m][n][0] = bv[n]; acc[m][n][1] = bv[n];
            acc[m][n][2] = bv[n]; acc[m][n][3] = bv[n];
        }

    const int srow = lane >> 4;
    const int scp  = lane & 15;

    for (int kt = 0; kt < KT; ++kt) {
        const int fc = kt * 64;
        __syncthreads();
#pragma unroll
        for (int it = 0; it < 8; ++it) {
            int rbase = it * 16 + w * 4;
            int row = rbase + srow;
            int cg = scp ^ (row & 7);
            int col0 = fc + cg * 4;
            const float* src = xbase + (long)row * F + ((col0 < F) ? col0 : 0);
            gld16(src, (char*)As + rbase * 256);
        }
#pragma unroll
        for (int it = 0; it < 4; ++it) {
            int rb = it * 32 + w * 8;
            const char* src = (const char*)wh2 + (long)kt * 16384 + rb * 128 + lane * 16;
            gld16(src, (char*)Bs + rb * 128);
        }
        __syncthreads();

#pragma unroll
        for (int ks = 0; ks < 2; ++ks) {
            half8 b[4];
#pragma unroll
            for (int n = 0; n < 4; ++n) {
                int col = wn * 64 + n * 16 + lr;
                int ch = (ks * 4 + kg) ^ (col & 7);
                b[n] = *(const half8*)((const char*)Bs + col * 128 + ch * 16);
            }
#pragma unroll
            for (int m = 0; m < 4; ++m) {
                int row = wm * 64 + m * 16 + lr;
                int c0 = ks * 8 + kg * 2;
                const char* base = (const char*)As + row * 256;
                float4 x0 = *(const float4*)(base + (((c0)     ^ (row & 7)) << 4));
                float4 x1 = *(const float4*)(base + (((c0 + 1) ^ (row & 7)) << 4));
                half8 a = pack8(x0, x1);
#pragma unroll
                for (int n = 0; n < 4; ++n)
                    acc[m][n] = __builtin_amdgcn_mfma_f32_16x16x32_f16(a, b[n], acc[m][n], 0, 0, 0);
            }
        }
    }

    __syncthreads();

    if (l_hop < L - 1) {
        int br = aid[l_hop] - row0;
        if (br >= 0 && br < 128 && (br >> 6) == wm && ((br >> 2) & 3) == kg) {
            int msel = (br >> 4) & 3, rsel = br & 3;
#pragma unroll
            for (int n = 0; n < 4; ++n) {
                float vsel = 0.f;
#pragma unroll
                for (int m = 0; m < 4; ++m)
#pragma unroll
                    for (int r = 0; r < 4; ++r)
                        if (m == msel && r == rsel) vsel = acc[m][n][r];
                hsel[l_hop * D + wn * 64 + n * 16 + lr] = vsel;
            }
        }
    }

    float cmax[4];
#pragma unroll
    for (int n = 0; n < 4; ++n) {
        float m0 = acc[0][n][0];
#pragma unroll
        for (int m = 0; m < 4; ++m)
#pragma unroll
            for (int r = 0; r < 4; ++r) m0 = fmaxf(m0, acc[m][n][r]);
        m0 = fmaxf(m0, __shfl_xor(m0, 16, 64));
        m0 = fmaxf(m0, __shfl_xor(m0, 32, 64));
        cmax[n] = m0;
    }
    float* wmaxp = (float*)As;
    if (kg == 0) {
#pragma unroll
        for (int n = 0; n < 4; ++n)
            wmaxp[wm * 128 + wn * 64 + n * 16 + lr] = cmax[n];
    }
    __syncthreads();
    if (tid < 128) {
        float mval = fmaxf(wmaxp[tid], wmaxp[128 + tid]);
        atomicMax(&hmaxk[l_hop * D + tid], encf(mval));
    }
}

// ---- gi for all 8 GRU steps ----
__global__ void k_gi(const float* __restrict__ Wih, const float* __restrict__ bih,
                     const float* __restrict__ pn, const unsigned* __restrict__ hmaxk,
                     const float* __restrict__ hsel, float* __restrict__ gi) {
    __shared__ float xs[L][3 * D];
    const int tid = threadIdx.x;
    for (int i = tid; i < L * 3 * D; i += 256) {
        int t = i / (3 * D), k = i % (3 * D);
        float x;
        if (t == 0) {
            x = (k < 2 * D) ? 0.0f : pn[k - 2 * D];
        } else {
            if (k < D)            x = decf(hmaxk[(t - 1) * D + k]);
            else if (k < 2 * D)   x = hsel[(t - 1) * D + (k - D)];
            else                  x = pn[t * D + (k - 2 * D)];
        }
        xs[t][k] = x;
    }
    __syncthreads();

    const int lane = tid & 63;
    const int row = blockIdx.x * 4 + (tid >> 6);
    const float* wr = Wih + (long)row * 3 * D;
    float s[L];
#pragma unroll
    for (int t = 0; t < L; ++t) s[t] = 0.f;
#pragma unroll
    for (int c = 0; c < 6; ++c) {
        int k = lane + c * 64;
        float wv = wr[k];
#pragma unroll
        for (int t = 0; t < L; ++t) s[t] = fmaf(wv, xs[t][k], s[t]);
    }
#pragma unroll
    for (int t = 0; t < L; ++t)
        for (int off = 1; off < 64; off <<= 1) s[t] += __shfl_xor(s[t], off, 64);
    if (lane == 0) {
        float b = bih[row];
#pragma unroll
        for (int t = 0; t < L; ++t) gi[t * 3 * H + row] = s[t] + b;
    }
}

// ---- all 8 GRU steps in ONE kernel ----
__global__ __launch_bounds__(256, 1)
void k_gru(const float* __restrict__ Whh, const float* __restrict__ bhh,
           const float* __restrict__ gi, const float* __restrict__ query,
           float* __restrict__ hbuf, unsigned* __restrict__ cnt) {
    const int tid = threadIdx.x;
    const int lane = tid & 63;
    const int j = blockIdx.x * 4 + (tid >> 6);

    float wr[7], wz[7], wnn[7];
#pragma unroll
    for (int c = 0; c < 7; ++c) {
        int i = lane + c * 64;
        bool ok = i < H;
        wr[c]  = ok ? Whh[(long)j * H + i]           : 0.f;
        wz[c]  = ok ? Whh[(long)(H + j) * H + i]     : 0.f;
        wnn[c] = ok ? Whh[(long)(2 * H + j) * H + i] : 0.f;
    }
    float b_r = 0.f, b_z = 0.f, b_n = 0.f;
    if (lane == 0) { b_r = bhh[j]; b_z = bhh[H + j]; b_n = bhh[2 * H + j]; }

    for (int t = 0; t < L; ++t) {
        const float* hin = (t == 0) ? query : (hbuf + ((t - 1) & 1) * H);
        float* hout = hbuf + (t & 1) * H;
        float pr = 0.f, pz = 0.f, pn2 = 0.f;
#pragma unroll
        for (int c = 0; c < 7; ++c) {
            int i = lane + c * 64;
            float hv = 0.f;
            if (i < H)
                hv = (t == 0) ? hin[i]
                              : __hip_atomic_load(hin + i, __ATOMIC_RELAXED,
                                                  __HIP_MEMORY_SCOPE_AGENT);
            pr  = fmaf(wr[c],  hv, pr);
            pz  = fmaf(wz[c],  hv, pz);
            pn2 = fmaf(wnn[c], hv, pn2);
        }
        for (int off = 1; off < 64; off <<= 1) {
            pr  += __shfl_xor(pr, off, 64);
            pz  += __shfl_xor(pz, off, 64);
            pn2 += __shfl_xor(pn2, off, 64);
        }
        if (lane == 0) {
            const float* gt = gi + t * 3 * H;
            float hprev = (t == 0) ? hin[j]
                                   : __hip_atomic_load(hin + j, __ATOMIC_RELAXED,
                                                       __HIP_MEMORY_SCOPE_AGENT);
            float r  = sigmoidf_(gt[j] + pr + b_r);
            float z  = sigmoidf_(gt[H + j] + pz + b_z);
            float nn = tanhf(gt[2 * H + j] + r * (pn2 + b_n));
            float hv = (1.0f - z) * nn + z * hprev;
            __hip_atomic_store(hout + j, hv, __ATOMIC_RELAXED,
                               __HIP_MEMORY_SCOPE_AGENT);
        }
        if (t < L - 1) {
            __syncthreads();
            if (tid == 0) {
                __hip_atomic_fetch_add(cnt, 1u, __ATOMIC_RELEASE,
                                       __HIP_MEMORY_SCOPE_AGENT);
                unsigned target = (unsigned)GRU_BLOCKS * (t + 1);
                while (__hip_atomic_load(cnt, __ATOMIC_ACQUIRE,
                                         __HIP_MEMORY_SCOPE_AGENT) < target)
                    __builtin_amdgcn_s_sleep(2);
            }
            __syncthreads();
        }
    }
}

// ---- hSt + v + u0 + c in one block ----
__global__ void k_final(const float* __restrict__ qt, const float* __restrict__ Wfs,
                        const float* __restrict__ bfs, const float* __restrict__ Wfp,
                        const float* __restrict__ bfp, const float* __restrict__ bfa,
                        const float* __restrict__ Wfa, const unsigned* __restrict__ hmaxk,
                        float* __restrict__ v, float* __restrict__ scal,
                        float* __restrict__ logits) {
    __shared__ float hs[D];
    int tid = threadIdx.x, lane = tid & 63, wid = tid >> 6;
#pragma unroll
    for (int dd = 0; dd < 8; ++dd) {
        int d = wid * 8 + dd;
        float s = 0.f;
#pragma unroll
        for (int c = 0; c < 7; ++c) {
            int i = lane + c * 64;
            if (i < H) s = fmaf(qt[i], Wfs[(long)d * H + i], s);
        }
        for (int off = 1; off < 64; off <<= 1) s += __shfl_xor(s, off, 64);
        if (lane == 0) hs[d] = s + bfs[d];
    }
    __syncthreads();
    if (tid < F) {
        float s = 0.f;
#pragma unroll 16
        for (int d = 0; d < D; ++d) s = fmaf(hs[d], Wfa[(long)d * F + tid], s);
        v[tid] = s;
    } else if (tid == F) {
        float s = bfp[0];
        for (int d = 0; d < D; ++d) {
            s = fmaf(hs[d], Wfp[d], s);
            s = fmaf(decf(hmaxk[(L - 1) * D + d]), Wfp[D + d], s);
        }
        logits[0] = s;
    } else if (tid == F + 1) {
        float c2 = 0.f;
        for (int d = 0; d < D; ++d) c2 = fmaf(hs[d], bfa[d], c2);
        scal[0] = c2;
    }
}

// ---- uks logits ----
__global__ void k_uks(const float* __restrict__ nb7, const float* __restrict__ v,
                      const float* __restrict__ scal, float* __restrict__ logits) {
    long n = (long)blockIdx.x * 4 + (threadIdx.x >> 6);
    int lane = threadIdx.x & 63;
    const float* row = nb7 + n * F;
    float s = 0.f;
    for (int f = lane; f < F; f += 64) s = fmaf(v[f], row[f], s);
    for (int off = 1; off < 64; off <<= 1) s += __shfl_xor(s, off, 64);
    if (lane == 0) logits[1 + n] = s + scal[0];
}

// ---- softmax reduce ----
__global__ void k_sm12(const float* __restrict__ logits, float* __restrict__ scal) {
    __shared__ float sm[16], ss[16];
    int tid = threadIdx.x, lane = tid & 63, wid = tid >> 6;
    float m = -3.4e38f, s = 0.f;
    for (int i = tid; i <= N; i += 1024) {
        float x = logits[i];
        if (x > m) { s = s * __expf(m - x) + 1.0f; m = x; }
        else       { s += __expf(x - m); }
    }
    for (int off = 1; off < 64; off <<= 1) {
        float m2 = __shfl_xor(m, off, 64);
        float s2 = __shfl_xor(s, off, 64);
        float M = fmaxf(m, m2);
        s = s * __expf(m - M) + s2 * __expf(m2 - M);
        m = M;
    }
    if (lane == 0) { sm[wid] = m; ss[wid] = s; }
    __syncthreads();
    if (tid == 0) {
        float M = sm[0], S = 0.f;
        for (int k = 1; k < 16; ++k) M = fmaxf(M, sm[k]);
        for (int k = 0; k < 16; ++k) S += ss[k] * __expf(sm[k] - M);
        scal[1] = M; scal[2] = S;
    }
}

__global__ void k_sm3(const float* __restrict__ logits, const float* __restrict__ scal,
                      float* __restrict__ out) {
    int i = blockIdx.x * 256 + threadIdx.x;
    if (i <= N) out[i] = __expf(logits[i] - scal[1]) / scal[2];
}

extern "C" void kernel_launch(void* const* d_in, const int* in_sizes, int n_in,
                              void* d_out, int out_size, void* d_ws, size_t ws_size,
                              hipStream_t stream) {
    const float* query = (const float*)d_in[0];
    const float* pn    = (const float*)d_in[1];
    const float* nb    = (const float*)d_in[2];
    const int*   aid   = (const int*)d_in[3];
    const float* Wih   = (const float*)d_in[4];
    const float* Whh   = (const float*)d_in[5];
    const float* bih   = (const float*)d_in[6];
    const float* bhh   = (const float*)d_in[7];
    const float* Wfa   = (const float*)d_in[8];
    const float* bfa   = (const float*)d_in[9];
    const float* Wfs   = (const float*)d_in[10];
    const float* bfs   = (const float*)d_in[11];
    const float* Wfp   = (const float*)d_in[12];
    const float* bfp   = (const float*)d_in[13];

    float* ws = (float*)d_ws;
    unsigned short* wh2    = (unsigned short*)(ws + WS_WH2);
    unsigned*       hmaxk  = (unsigned*)(ws + WS_HMAXK);
    unsigned*       cnt    = (unsigned*)(ws + WS_CNT);
    unsigned*       hmaxk2 = (unsigned*)(ws + WS_HMAXK2);
    float* hsel   = ws + WS_HSEL;
    float* hsel2  = ws + WS_HSEL2;
    float* gi     = ws + WS_GI;
    float* hbuf   = ws + WS_HBUF;
    float* v      = ws + WS_V;
    float* scal   = ws + WS_SCAL;
    float* logits = ws + WS_LOGITS;
    float* out    = (float*)d_out;

    k_prep<<<(KT * 128 * 8 + 255) / 256, 256, 0, stream>>>(Wfa, wh2, hmaxk, cnt);
    k_big <<<L * 256, 256, 0, stream>>>(nb, wh2, bfa, aid, hmaxk, hsel);
    // ---- TIMING INSTRUMENT: duplicate k_big into scratch; outputs unused.
    // Total dur = (r9 total) + k_big duration -> decomposes k_big vs chain.
    k_big <<<L * 256, 256, 0, stream>>>(nb, wh2, bfa, aid, hmaxk2, hsel2);

    k_gi  <<<303, 256, 0, stream>>>(Wih, bih, pn, hmaxk, hsel, gi);
    k_gru <<<GRU_BLOCKS, 256, 0, stream>>>(Whh, bhh, gi, query, hbuf, cnt);

    const float* qt = hbuf + ((L - 1) & 1) * H;
    k_final<<<1, 1024, 0, stream>>>(qt, Wfs, bfs, Wfp, bfp, bfa, Wfa, hmaxk, v, scal, logits);
    k_uks  <<<N / 4, 256, 0, stream>>>(nb + (long)(L - 1) * N * F, v, scal, logits);

    k_sm12<<<1, 1024, 0, stream>>>(logits, scal);
    k_sm3 <<<(N + 1 + 255) / 256, 256, 0, stream>>>(logits, scal, out);
}

// Round 15
// 195.106 us; speedup vs baseline: 1.7296x; 1.7296x over previous
//
#include <hip/hip_runtime.h>
#include <math.h>

#define L 8
#define N 32768
#define H 404
#define D 128
#define F 532
#define KT 9              // K-tiles of 64 (64*9=576; cols >=532 are zero in B)
#define GRU_BLOCKS 101    // one wave per hidden index

typedef __attribute__((ext_vector_type(8))) _Float16 half8;
typedef __attribute__((ext_vector_type(4))) float f32x4;
typedef __attribute__((address_space(3))) unsigned int as3_u32;
typedef __attribute__((address_space(1))) unsigned int as1_u32;

// workspace layout (float offsets)
#define WS_WH2     0                        // 9*128*64 fp16 = 36864 floats
#define WS_HMAXK   (WS_WH2 + 36864)         // 8*128 uint keys
#define WS_HSEL    (WS_HMAXK + L * D)       // 7*128
#define WS_GI      (WS_HSEL + (L - 1) * D)  // 8*1212
#define WS_HBUF    (WS_GI + L * 3 * H)      // 2*404
#define WS_HS      (WS_HBUF + 2 * H)        // 128
#define WS_SCAL    (WS_HS + D)              // [1]=M, [2]=S
#define WS_CNT     (WS_SCAL + 4)            // gru barrier counter
#define WS_PM      (WS_CNT + 4)             // 256 block partial max
#define WS_PS      (WS_PM + 256)            // 256 block partial sum
#define WS_LOGITS  (WS_PS + 256)            // 32769

__device__ __forceinline__ unsigned encf(float f) {
    unsigned u = __float_as_uint(f);
    return (u & 0x80000000u) ? ~u : (u | 0x80000000u);
}
__device__ __forceinline__ float decf(unsigned u) {
    unsigned b = (u & 0x80000000u) ? (u ^ 0x80000000u) : ~u;
    return __uint_as_float(b);
}
__device__ __forceinline__ float sigmoidf_(float x) {
    return 1.0f / (1.0f + __expf(-x));
}
__device__ __forceinline__ unsigned pk_f16(float a, float b) {
    auto h = __builtin_amdgcn_cvt_pkrtz(a, b);
    return *(unsigned*)&h;
}
__device__ __forceinline__ half8 pack8(float4 x0, float4 x1) {
    uint4 u = { pk_f16(x0.x, x0.y), pk_f16(x0.z, x0.w),
                pk_f16(x1.x, x1.y), pk_f16(x1.z, x1.w) };
    return *(half8*)&u;
}
__device__ __forceinline__ void gld16(const void* g, void* l) {
    __builtin_amdgcn_global_load_lds((const as1_u32*)g, (as3_u32*)l, 16, 0, 0);
}
__device__ __forceinline__ float aload(const float* p) {
    return __hip_atomic_load(p, __ATOMIC_RELAXED, __HIP_MEMORY_SCOPE_AGENT);
}
__device__ __forceinline__ void astore(float* p, float v) {
    __hip_atomic_store(p, v, __ATOMIC_RELAXED, __HIP_MEMORY_SCOPE_AGENT);
}

// ---- prep: pre-swizzled fp16 B tiles; init keys ----
__global__ void k_prep(const float* __restrict__ Wfa, unsigned short* __restrict__ wh2,
                       unsigned* __restrict__ keys, unsigned* __restrict__ cnt) {
    int i = blockIdx.x * 256 + threadIdx.x;
    if (i < L * D) keys[i] = 0u;           // decodes below all finite values
    if (i == 2000) *cnt = 0u;
    if (i >= KT * 128 * 8) return;
    int kt = i / (128 * 8);
    int rem = i - kt * 128 * 8;
    int c = rem >> 3, j = rem & 7;
    int k0 = kt * 64 + (j ^ (c & 7)) * 8;
    unsigned short v[8];
#pragma unroll
    for (int e = 0; e < 8; ++e) {
        int k = k0 + e;
        float x = (k < F) ? Wfa[c * F + k] : 0.0f;
        _Float16 h = (_Float16)x;
        v[e] = *(unsigned short*)&h;
    }
    *(uint4*)(wh2 + (long)i * 8) = *(uint4*)v;
}

// ---- big einsum (r9 structure). HOP7=0: hops 0-6, hsel+hmax.
//      HOP7=1: hop 7 only, hmax + in-register uks + block softmax partials. ----
template<int HOP7>
__global__ __launch_bounds__(256, 3)
void k_big(const float* __restrict__ nb, const unsigned short* __restrict__ wh2,
           const float* __restrict__ bfa, const int* __restrict__ aid,
           unsigned* __restrict__ hmaxk, float* __restrict__ hsel,
           const float* __restrict__ hs_ws, float* __restrict__ logits,
           float* __restrict__ pm, float* __restrict__ ps) {
    __shared__ float As[128 * 64];          // 32 KB
    __shared__ unsigned short Bs[128 * 64]; // 16 KB
    __shared__ float sm2[2], ss2[2];

    const int bid = blockIdx.x;
    const int l_hop = HOP7 ? 7 : (bid >> 8);
    const int row0 = HOP7 ? bid * 128 : (bid & 255) * 128;
    const int tid = threadIdx.x;
    const int lane = tid & 63, w = tid >> 6;
    const int wm = w >> 1, wn = w & 1;
    const int lr = lane & 15, kg = lane >> 4;

    const float* xbase = nb + ((long)l_hop * N + row0) * F;

    f32x4 acc[4][4];
    float bv[4];
#pragma unroll
    for (int n = 0; n < 4; ++n) bv[n] = bfa[wn * 64 + n * 16 + lr];
#pragma unroll
    for (int m = 0; m < 4; ++m)
#pragma unroll
        for (int n = 0; n < 4; ++n) {
            acc[m][n][0] = bv[n]; acc[m][n][1] = bv[n];
            acc[m][n][2] = bv[n]; acc[m][n][3] = bv[n];
        }

    const int srow = lane >> 4;
    const int scp  = lane & 15;

    for (int kt = 0; kt < KT; ++kt) {
        const int fc = kt * 64;
        __syncthreads();
#pragma unroll
        for (int it = 0; it < 8; ++it) {
            int rbase = it * 16 + w * 4;
            int row = rbase + srow;
            int cg = scp ^ (row & 7);
            int col0 = fc + cg * 4;
            const float* src = xbase + (long)row * F + ((col0 < F) ? col0 : 0);
            gld16(src, (char*)As + rbase * 256);
        }
#pragma unroll
        for (int it = 0; it < 4; ++it) {
            int rb = it * 32 + w * 8;
            const char* src = (const char*)wh2 + (long)kt * 16384 + rb * 128 + lane * 16;
            gld16(src, (char*)Bs + rb * 128);
        }
        __syncthreads();

#pragma unroll
        for (int ks = 0; ks < 2; ++ks) {
            half8 b[4];
#pragma unroll
            for (int n = 0; n < 4; ++n) {
                int col = wn * 64 + n * 16 + lr;
                int ch = (ks * 4 + kg) ^ (col & 7);
                b[n] = *(const half8*)((const char*)Bs + col * 128 + ch * 16);
            }
#pragma unroll
            for (int m = 0; m < 4; ++m) {
                int row = wm * 64 + m * 16 + lr;
                int c0 = ks * 8 + kg * 2;
                const char* base = (const char*)As + row * 256;
                float4 x0 = *(const float4*)(base + (((c0)     ^ (row & 7)) << 4));
                float4 x1 = *(const float4*)(base + (((c0 + 1) ^ (row & 7)) << 4));
                half8 a = pack8(x0, x1);
#pragma unroll
                for (int n = 0; n < 4; ++n)
                    acc[m][n] = __builtin_amdgcn_mfma_f32_16x16x32_f16(a, b[n], acc[m][n], 0, 0, 0);
            }
        }
    }

    __syncthreads();   // MFMA LDS reads done; As reusable

    if (!HOP7) {
        // selected-action row (compile-time acc indexing)
        int br = aid[l_hop] - row0;
        if (br >= 0 && br < 128 && (br >> 6) == wm && ((br >> 2) & 3) == kg) {
            int msel = (br >> 4) & 3, rsel = br & 3;
#pragma unroll
            for (int n = 0; n < 4; ++n) {
                float vsel = 0.f;
#pragma unroll
                for (int m = 0; m < 4; ++m)
#pragma unroll
                    for (int r = 0; r < 4; ++r)
                        if (m == msel && r == rsel) vsel = acc[m][n][r];
                hsel[l_hop * D + wn * 64 + n * 16 + lr] = vsel;
            }
        }
    } else {
        // ---- uks[row] = sum_col hs[col] * acc (bias folded in acc init) ----
        float hsv[4];
#pragma unroll
        for (int n = 0; n < 4; ++n) hsv[n] = hs_ws[wn * 64 + n * 16 + lr];
        float p[4][4];
#pragma unroll
        for (int m = 0; m < 4; ++m)
#pragma unroll
            for (int r = 0; r < 4; ++r) {
                float s = hsv[0] * acc[m][0][r];
                s = fmaf(hsv[1], acc[m][1][r], s);
                s = fmaf(hsv[2], acc[m][2][r], s);
                s = fmaf(hsv[3], acc[m][3][r], s);
#pragma unroll
                for (int off = 1; off < 16; off <<= 1)
                    s += __shfl_xor(s, off, 64);   // reduce within 16-lane kg group
                p[m][r] = s;
            }
        float* part = (float*)As;   // [2 wn][128 rows]
        if (lr == 0) {
#pragma unroll
            for (int m = 0; m < 4; ++m)
#pragma unroll
                for (int r = 0; r < 4; ++r)
                    part[wn * 128 + wm * 64 + m * 16 + kg * 4 + r] = p[m][r];
        }
        __syncthreads();
        float val = -3.4e38f, sv = 0.f;
        if (tid < 128) {
            val = part[tid] + part[128 + tid];
            logits[1 + row0 + tid] = val;
            sv = 1.0f;
        }
        // block online softmax partial over the 128 values (waves 0,1)
        float mv = val;
        for (int off = 1; off < 64; off <<= 1) {
            float m2 = __shfl_xor(mv, off, 64);
            float s2 = __shfl_xor(sv, off, 64);
            float M = fmaxf(mv, m2);
            sv = sv * __expf(mv - M) + s2 * __expf(m2 - M);
            mv = M;
        }
        if (lane == 0 && w < 2) { sm2[w] = mv; ss2[w] = sv; }
        __syncthreads();
        if (tid == 0) {
            float M = fmaxf(sm2[0], sm2[1]);
            float S = ss2[0] * __expf(sm2[0] - M) + ss2[1] * __expf(sm2[1] - M);
            pm[bid] = M; ps[bid] = S;
        }
        __syncthreads();   // part (As) free again for hmax below
    }

    // column max -> atomicMax (all hops; hop7 feeds u0)
    float cmax[4];
#pragma unroll
    for (int n = 0; n < 4; ++n) {
        float m0 = acc[0][n][0];
#pragma unroll
        for (int m = 0; m < 4; ++m)
#pragma unroll
            for (int r = 0; r < 4; ++r) m0 = fmaxf(m0, acc[m][n][r]);
        m0 = fmaxf(m0, __shfl_xor(m0, 16, 64));
        m0 = fmaxf(m0, __shfl_xor(m0, 32, 64));
        cmax[n] = m0;
    }
    float* wmaxp = (float*)As;   // [2][128]
    if (kg == 0) {
#pragma unroll
        for (int n = 0; n < 4; ++n)
            wmaxp[wm * 128 + wn * 64 + n * 16 + lr] = cmax[n];
    }
    __syncthreads();
    if (tid < 128) {
        float mval = fmaxf(wmaxp[tid], wmaxp[128 + tid]);
        atomicMax(&hmaxk[l_hop * D + tid], encf(mval));
    }
}

// ---- gi for all 8 GRU steps (uses hmax[0..6] only) ----
__global__ void k_gi(const float* __restrict__ Wih, const float* __restrict__ bih,
                     const float* __restrict__ pn, const unsigned* __restrict__ hmaxk,
                     const float* __restrict__ hsel, float* __restrict__ gi) {
    __shared__ float xs[L][3 * D];
    const int tid = threadIdx.x;
    for (int i = tid; i < L * 3 * D; i += 256) {
        int t = i / (3 * D), k = i % (3 * D);
        float x;
        if (t == 0) {
            x = (k < 2 * D) ? 0.0f : pn[k - 2 * D];
        } else {
            if (k < D)            x = decf(hmaxk[(t - 1) * D + k]);
            else if (k < 2 * D)   x = hsel[(t - 1) * D + (k - D)];
            else                  x = pn[t * D + (k - 2 * D)];
        }
        xs[t][k] = x;
    }
    __syncthreads();

    const int lane = tid & 63;
    const int row = blockIdx.x * 4 + (tid >> 6);
    const float* wr = Wih + (long)row * 3 * D;
    float s[L];
#pragma unroll
    for (int t = 0; t < L; ++t) s[t] = 0.f;
#pragma unroll
    for (int c = 0; c < 6; ++c) {
        int k = lane + c * 64;
        float wv = wr[k];
#pragma unroll
        for (int t = 0; t < L; ++t) s[t] = fmaf(wv, xs[t][k], s[t]);
    }
#pragma unroll
    for (int t = 0; t < L; ++t)
        for (int off = 1; off < 64; off <<= 1) s[t] += __shfl_xor(s[t], off, 64);
    if (lane == 0) {
        float b = bih[row];
#pragma unroll
        for (int t = 0; t < L; ++t) gi[t * 3 * H + row] = s[t] + b;
    }
}

// ---- 8 GRU steps + hSt, one kernel; counter barriers ----
__global__ __launch_bounds__(256, 1)
void k_gru(const float* __restrict__ Whh, const float* __restrict__ bhh,
           const float* __restrict__ gi, const float* __restrict__ query,
           const float* __restrict__ Wfs, const float* __restrict__ bfs,
           float* __restrict__ hbuf, float* __restrict__ hs_ws,
           unsigned* __restrict__ cnt) {
    const int tid = threadIdx.x;
    const int lane = tid & 63;
    const int bid = blockIdx.x;
    const int j = bid * 4 + (tid >> 6);

    float wr[7], wz[7], wnn[7];
#pragma unroll
    for (int c = 0; c < 7; ++c) {
        int i = lane + c * 64;
        bool ok = i < H;
        wr[c]  = ok ? Whh[(long)j * H + i]           : 0.f;
        wz[c]  = ok ? Whh[(long)(H + j) * H + i]     : 0.f;
        wnn[c] = ok ? Whh[(long)(2 * H + j) * H + i] : 0.f;
    }
    float b_r = 0.f, b_z = 0.f, b_n = 0.f;
    if (lane == 0) { b_r = bhh[j]; b_z = bhh[H + j]; b_n = bhh[2 * H + j]; }

    for (int t = 0; t < L; ++t) {
        const float* hin = (t == 0) ? query : (hbuf + ((t - 1) & 1) * H);
        float* hout = hbuf + (t & 1) * H;
        float pr = 0.f, pz = 0.f, pn2 = 0.f;
#pragma unroll
        for (int c = 0; c < 7; ++c) {
            int i = lane + c * 64;
            float hv = 0.f;
            if (i < H) hv = (t == 0) ? hin[i] : aload(hin + i);
            pr  = fmaf(wr[c],  hv, pr);
            pz  = fmaf(wz[c],  hv, pz);
            pn2 = fmaf(wnn[c], hv, pn2);
        }
        for (int off = 1; off < 64; off <<= 1) {
            pr  += __shfl_xor(pr, off, 64);
            pz  += __shfl_xor(pz, off, 64);
            pn2 += __shfl_xor(pn2, off, 64);
        }
        if (lane == 0) {
            const float* gt = gi + t * 3 * H;
            float hprev = (t == 0) ? hin[j] : aload(hin + j);
            float r  = sigmoidf_(gt[j] + pr + b_r);
            float z  = sigmoidf_(gt[H + j] + pz + b_z);
            float nn = tanhf(gt[2 * H + j] + r * (pn2 + b_n));
            astore(hout + j, (1.0f - z) * nn + z * hprev);
        }
        // barrier after every step (incl. t=7, so hbuf[1] visible for hSt)
        __syncthreads();
        if (tid == 0) {
            __hip_atomic_fetch_add(cnt, 1u, __ATOMIC_RELEASE,
                                   __HIP_MEMORY_SCOPE_AGENT);
            unsigned target = (unsigned)GRU_BLOCKS * (t + 1);
            while (__hip_atomic_load(cnt, __ATOMIC_ACQUIRE,
                                     __HIP_MEMORY_SCOPE_AGENT) < target)
                __builtin_amdgcn_s_sleep(2);
        }
        __syncthreads();
    }

    // ---- hSt = W_fs qt + b_fs : blocks 0..31, wave per d ----
    if (bid < 32) {
        const float* qt = hbuf + H;    // hbuf[1]
        int d = bid * 4 + (tid >> 6);
        float s = 0.f;
#pragma unroll
        for (int c = 0; c < 7; ++c) {
            int i = lane + c * 64;
            if (i < H) s = fmaf(aload(qt + i), Wfs[(long)d * H + i], s);
        }
        for (int off = 1; off < 64; off <<= 1) s += __shfl_xor(s, off, 64);
        if (lane == 0) astore(&hs_ws[d], s + bfs[d]);
    }
}

// ---- u0 + reduce 256 block partials -> M, S ----
__global__ void k_sm12(const float* __restrict__ hs_ws, const float* __restrict__ Wfp,
                       const float* __restrict__ bfp, const unsigned* __restrict__ hmaxk,
                       const float* __restrict__ pm, const float* __restrict__ ps,
                       float* __restrict__ logits, float* __restrict__ scal) {
    __shared__ float red[4], reds[4], u0sh;
    int tid = threadIdx.x, lane = tid & 63, wid = tid >> 6;
    // u0 (wave 0)
    if (tid < 64) {
        float s = hs_ws[tid] * Wfp[tid];
        s = fmaf(hs_ws[tid + 64], Wfp[tid + 64], s);
        s = fmaf(decf(hmaxk[(L - 1) * D + tid]),      Wfp[D + tid],      s);
        s = fmaf(decf(hmaxk[(L - 1) * D + tid + 64]), Wfp[D + tid + 64], s);
        for (int off = 1; off < 64; off <<= 1) s += __shfl_xor(s, off, 64);
        if (tid == 0) { u0sh = s + bfp[0]; logits[0] = u0sh; }
    }
    __syncthreads();
    // reduce partials (tid < 256 -> 4 waves)
    float m = -3.4e38f, s = 0.f;
    if (tid < 256) { m = pm[tid]; s = ps[tid]; }
    for (int off = 1; off < 64; off <<= 1) {
        float m2 = __shfl_xor(m, off, 64);
        float s2 = __shfl_xor(s, off, 64);
        float M = fmaxf(m, m2);
        s = s * __expf(m - M) + s2 * __expf(m2 - M);
        m = M;
    }
    if (lane == 0 && wid < 4) { red[wid] = m; reds[wid] = s; }
    __syncthreads();
    if (tid == 0) {
        float M = u0sh, S = 1.0f;   // fold u0
        for (int k = 0; k < 4; ++k) {
            float Mn = fmaxf(M, red[k]);
            S = S * __expf(M - Mn) + reds[k] * __expf(red[k] - Mn);
            M = Mn;
        }
        scal[1] = M; scal[2] = S;
    }
}

__global__ void k_sm3(const float* __restrict__ logits, const float* __restrict__ scal,
                      float* __restrict__ out) {
    int i = blockIdx.x * 256 + threadIdx.x;
    if (i <= N) out[i] = __expf(logits[i] - scal[1]) / scal[2];
}

extern "C" void kernel_launch(void* const* d_in, const int* in_sizes, int n_in,
                              void* d_out, int out_size, void* d_ws, size_t ws_size,
                              hipStream_t stream) {
    const float* query = (const float*)d_in[0];
    const float* pn    = (const float*)d_in[1];
    const float* nb    = (const float*)d_in[2];
    const int*   aid   = (const int*)d_in[3];
    const float* Wih   = (const float*)d_in[4];
    const float* Whh   = (const float*)d_in[5];
    const float* bih   = (const float*)d_in[6];
    const float* bhh   = (const float*)d_in[7];
    const float* Wfa   = (const float*)d_in[8];
    const float* bfa   = (const float*)d_in[9];
    const float* Wfs   = (const float*)d_in[10];
    const float* bfs   = (const float*)d_in[11];
    const float* Wfp   = (const float*)d_in[12];
    const float* bfp   = (const float*)d_in[13];

    float* ws = (float*)d_ws;
    unsigned short* wh2   = (unsigned short*)(ws + WS_WH2);
    unsigned*       hmaxk = (unsigned*)(ws + WS_HMAXK);
    unsigned*       cnt   = (unsigned*)(ws + WS_CNT);
    float* hsel   = ws + WS_HSEL;
    float* gi     = ws + WS_GI;
    float* hbuf   = ws + WS_HBUF;
    float* hs_ws  = ws + WS_HS;
    float* scal   = ws + WS_SCAL;
    float* pm     = ws + WS_PM;
    float* psum   = ws + WS_PS;
    float* logits = ws + WS_LOGITS;
    float* out    = (float*)d_out;

    k_prep<<<(KT * 128 * 8 + 255) / 256, 256, 0, stream>>>(Wfa, wh2, hmaxk, cnt);
    // hops 0..6 (chain-critical)
    k_big<0><<<(L - 1) * 256, 256, 0, stream>>>(nb, wh2, bfa, aid, hmaxk, hsel,
                                                hs_ws, logits, pm, psum);
    k_gi  <<<303, 256, 0, stream>>>(Wih, bih, pn, hmaxk, hsel, gi);
    k_gru <<<GRU_BLOCKS, 256, 0, stream>>>(Whh, bhh, gi, query, Wfs, bfs,
                                           hbuf, hs_ws, cnt);
    // hop 7: einsum + hmax7 + uks-from-acc + block softmax partials
    k_big<1><<<256, 256, 0, stream>>>(nb, wh2, bfa, aid, hmaxk, hsel,
                                      hs_ws, logits, pm, psum);
    k_sm12<<<1, 1024, 0, stream>>>(hs_ws, Wfp, bfp, hmaxk, pm, psum, logits, scal);
    k_sm3 <<<(N + 1 + 255) / 256, 256, 0, stream>>>(logits, scal, out);
}